// Round 1
// baseline (54149.420 us; speedup 1.0000x reference)
//
#include <hip/hip_runtime.h>
#include <hip/hip_bf16.h>

// LSTM: B=64, S=1024, I=H=O=1024. Strategy:
//  k_cvt    : Wx,Rh fp32 -> bf16
//  k_rein   : input [b][s][i] fp32 -> [s*64+b][i] bf16
//  k_gemm1  : xp[s*64+b][4096] bf16 = in @ Wx^T + bx + bh   (m97-style 128x128x64 MFMA)
//  k_lstm   : 1024 sequential steps; 4 independent batch-groups x 64 blocks,
//             Rh fragments persistent in VGPRs, h broadcast via global + LDS stage,
//             atomic spin barrier per group per step.
//  k_out    : out[b][o] = h_final @ Wout^T + bout (fp32)

using short8 = __attribute__((ext_vector_type(8))) short;
using f32x4  = __attribute__((ext_vector_type(4))) float;

__device__ __forceinline__ float bf2f(unsigned short u) {
  union { unsigned int i; float f; } v; v.i = ((unsigned int)u) << 16; return v.f;
}
__device__ __forceinline__ unsigned short f2bf(float f) {
  unsigned int x = __float_as_uint(f);
  x += 0x7fffu + ((x >> 16) & 1u);   // RNE (values are finite/normal here)
  return (unsigned short)(x >> 16);
}
__device__ __forceinline__ void gload16(unsigned short* lds, const unsigned short* g) {
  // async global->LDS, 16B/lane; LDS dest = wave-uniform base + lane*16
  __builtin_amdgcn_global_load_lds(
      (const __attribute__((address_space(1))) unsigned int*)(g),
      (__attribute__((address_space(3))) unsigned int*)(lds), 16, 0, 0);
}

// ---------------- weight convert fp32->bf16 ----------------
__global__ void k_cvt(const float* __restrict__ s, unsigned short* __restrict__ d, int n8) {
  int i = blockIdx.x * blockDim.x + threadIdx.x;
  if (i >= n8) return;
  const float4* sp = (const float4*)s + (size_t)i*2;
  float4 a = sp[0], b = sp[1];
  short8 o;
  o[0]=(short)f2bf(a.x); o[1]=(short)f2bf(a.y); o[2]=(short)f2bf(a.z); o[3]=(short)f2bf(a.w);
  o[4]=(short)f2bf(b.x); o[5]=(short)f2bf(b.y); o[6]=(short)f2bf(b.z); o[7]=(short)f2bf(b.w);
  *(short8*)(d + (size_t)i*8) = o;
}

// ---------------- input reorder+convert: [b][s][i] -> [s*64+b][i] ----------------
__global__ void k_rein(const float* __restrict__ in, unsigned short* __restrict__ out) {
  int r = blockIdx.x;               // r = s*64 + b
  int s = r >> 6, b = r & 63;
  const float* src = in + ((size_t)b*1024 + s)*1024;
  int t = threadIdx.x;              // 128 threads * 8 elems
  const float4* sp = (const float4*)(src + t*8);
  float4 a = sp[0], c = sp[1];
  short8 o;
  o[0]=(short)f2bf(a.x); o[1]=(short)f2bf(a.y); o[2]=(short)f2bf(a.z); o[3]=(short)f2bf(a.w);
  o[4]=(short)f2bf(c.x); o[5]=(short)f2bf(c.y); o[6]=(short)f2bf(c.z); o[7]=(short)f2bf(c.w);
  *(short8*)(out + (size_t)r*1024 + t*8) = o;
}

// ---------------- GEMM1: xp = A(65536x1024) * Bw^T(4096x1024) + bias, bf16 out ----------------
__launch_bounds__(256)
__global__ void k_gemm1(const unsigned short* __restrict__ A,
                        const unsigned short* __restrict__ Bw,
                        const float* __restrict__ bx,
                        const float* __restrict__ bh,
                        unsigned short* __restrict__ xp) {
  __shared__ alignas(16) unsigned short As[128*64];
  __shared__ alignas(16) unsigned short Bs[128*64];
  const int bm = blockIdx.x >> 5, bn = blockIdx.x & 31;
  const int lane = threadIdx.x & 63, wave = threadIdx.x >> 6;
  const int wm = wave >> 1, wn = wave & 1;
  const int cc = lane & 15, lg = lane >> 4;

  f32x4 acc[4][4];
  #pragma unroll
  for (int m=0;m<4;m++)
    #pragma unroll
    for (int n=0;n<4;n++) acc[m][n] = (f32x4){0.f,0.f,0.f,0.f};

  for (int kt=0; kt<16; ++kt) {
    #pragma unroll
    for (int ii=0; ii<4; ++ii) {
      int i = wave*4 + ii;                 // 16 issues of 8 rows each
      int row = i*8 + (lane>>3);
      int gc  = kt*64 + (lane&7)*8;
      gload16(&As[i*512], A  + (size_t)(bm*128+row)*1024 + gc);
      gload16(&Bs[i*512], Bw + (size_t)(bn*128+row)*1024 + gc);
    }
    asm volatile("s_waitcnt vmcnt(0)" ::: "memory");
    __syncthreads();
    #pragma unroll
    for (int k2=0;k2<2;k2++) {
      short8 af[4], bf[4];
      #pragma unroll
      for (int m=0;m<4;m++) af[m] = *(const short8*)&As[(wm*64 + m*16 + cc)*64 + k2*32 + lg*8];
      #pragma unroll
      for (int n=0;n<4;n++) bf[n] = *(const short8*)&Bs[(wn*64 + n*16 + cc)*64 + k2*32 + lg*8];
      #pragma unroll
      for (int m=0;m<4;m++)
        #pragma unroll
        for (int n=0;n<4;n++)
          acc[m][n] = __builtin_amdgcn_mfma_f32_16x16x32_bf16(af[m], bf[n], acc[m][n], 0, 0, 0);
    }
    __syncthreads();
  }
  #pragma unroll
  for (int n=0;n<4;n++) {
    int col = bn*128 + wn*64 + n*16 + cc;
    float bias = bx[col] + bh[col];
    #pragma unroll
    for (int m=0;m<4;m++) {
      int r0 = bm*128 + wm*64 + m*16 + lg*4;
      #pragma unroll
      for (int q=0;q<4;q++)
        xp[(size_t)(r0+q)*4096 + col] = f2bf(acc[m][n][q] + bias);
    }
  }
}

// ---------------- recurrence ----------------
// grid 256 = 4 groups (16 batches each) x 64 col-blocks (16 h-cols each).
// block = 512 thr = 8 waves: wave = nt(0..3) x kh(0..1).
// N-cols per block: 64 = 4 Ntiles; within Ntile col cc: gate=cc>>2, q=cc&3, j=jb0+nt*4+q.
// Rh B-frags persistent in regs (16x short8 per wave). c fp32 in regs (kh0 waves).
__launch_bounds__(512)
__global__ void k_lstm(const unsigned short* __restrict__ RhB,
                       const unsigned short* __restrict__ xp,
                       unsigned short* __restrict__ hbuf,   // [2][64][1024] bf16
                       unsigned int* __restrict__ bar) {    // [4][1024]
  __shared__ alignas(16) unsigned short hs[16*1032];        // 16 rows, +8 shorts pad
  __shared__ alignas(16) float red[4*64*4];
  const int tid = threadIdx.x;
  const int lane = tid & 63, wv = tid >> 6;
  const int nt = wv & 3, kh = wv >> 2;
  const int grp = blockIdx.x >> 6, cb = blockIdx.x & 63;
  const int bg0 = grp*16, jb0 = cb*16;
  const int cc = lane & 15, lg = lane >> 4;
  const int srow = tid >> 5, sidx = tid & 31;
  const int ncol = (cc>>2)*1024 + jb0 + nt*4 + (cc&3);

  short8 breg[16];                                          // Rh frags, static all steps
  {
    const unsigned short* bp = RhB + (size_t)ncol*1024 + kh*512 + lg*8;
    #pragma unroll
    for (int kk=0;kk<16;kk++) breg[kk] = *(const short8*)(bp + kk*32);
  }

  float c[4] = {0.f,0.f,0.f,0.f};

  for (int t=0; t<1024; ++t) {
    const unsigned short* hprev = hbuf + (t&1)*65536;
    unsigned short* hnext = hbuf + ((t+1)&1)*65536;

    float xr[4];
    if (kh == 0) {                                          // prefetch xp (indep of h)
      size_t base = (size_t)(t*64 + bg0 + lg*4)*4096 + ncol;
      #pragma unroll
      for (int q=0;q<4;q++) xr[q] = bf2f(xp[base + (size_t)q*4096]);
    }

    {                                                       // stage h slice -> LDS (padded rows)
      const unsigned short* gsrc = hprev + (size_t)(bg0+srow)*1024 + sidx*8;
      #pragma unroll
      for (int j=0;j<4;j++) {
        short8 v = *(const short8*)(gsrc + j*256);
        *(short8*)&hs[srow*1032 + sidx*8 + j*256] = v;
      }
    }
    __syncthreads();

    f32x4 acc = (f32x4){0.f,0.f,0.f,0.f};
    #pragma unroll
    for (int kk=0;kk<16;kk++) {
      short8 a = *(const short8*)&hs[cc*1032 + kh*512 + kk*32 + lg*8];
      acc = __builtin_amdgcn_mfma_f32_16x16x32_bf16(a, breg[kk], acc, 0, 0, 0);
    }

    if (kh == 1) *(f32x4*)&red[(nt*64+lane)*4] = acc;       // K-half partial
    __syncthreads();

    if (kh == 0) {
      f32x4 r2 = *(const f32x4*)&red[(nt*64+lane)*4];
      #pragma unroll
      for (int q=0;q<4;q++) {
        float v = acc[q] + r2[q] + xr[q];                   // g (bias already in xp)
        // gather 4 gates for (b,j): lanes differ in bits 2,3 of cc
        float p  = __shfl_xor(v, 4);
        float gA = (cc & 4) ? p : v;                        // gate 0 or 2 of pair
        float gB = (cc & 4) ? v : p;                        // gate 1 or 3
        float qA = __shfl_xor(gA, 8);
        float qB = __shfl_xor(gB, 8);
        float gz = (cc & 8) ? qA : gA;
        float gi = (cc & 8) ? qB : gB;
        float gf = (cc & 8) ? gA : qA;
        float go = (cc & 8) ? gB : qB;
        float zt = 2.f/(1.f+__expf(-2.f*gz)) - 1.f;
        float is = 1.f/(1.f+__expf(-gi));
        float fs = 1.f/(1.f+__expf(-gf));
        float os = 1.f/(1.f+__expf(-go));
        float cn = fs*c[q] + is*zt;
        c[q] = cn;
        float hv = os*(2.f/(1.f+__expf(-2.f*cn)) - 1.f);
        if (cc < 4)                                         // gate-0 lanes write h
          hnext[(size_t)(bg0 + lg*4 + q)*1024 + jb0 + nt*4 + cc] = f2bf(hv);
      }
    }

    __threadfence();                                        // agent release of h stores
    __syncthreads();
    if (tid == 0) {
      __hip_atomic_fetch_add(&bar[grp*1024 + t], 1u, __ATOMIC_RELEASE, __HIP_MEMORY_SCOPE_AGENT);
      unsigned int spins = 0;
      while (__hip_atomic_load(&bar[grp*1024 + t], __ATOMIC_ACQUIRE, __HIP_MEMORY_SCOPE_AGENT) < 64u) {
        __builtin_amdgcn_s_sleep(2);
        if (++spins > 100000u) break;                       // bail-out: no hangs
      }
    }
    __syncthreads();
  }
}

// ---------------- final: out = h @ Wout^T + bout (fp32) ----------------
__global__ void k_out(const unsigned short* __restrict__ h,
                      const float* __restrict__ Wout,
                      const float* __restrict__ bout,
                      float* __restrict__ out) {
  __shared__ float hsf[1024];
  const int b = blockIdx.x >> 2, oc = blockIdx.x & 3;
  const int tid = threadIdx.x;
  const unsigned short* hr = h + (size_t)b*1024;
  #pragma unroll
  for (int j=0;j<4;j++) hsf[tid*4+j] = bf2f(hr[tid*4+j]);
  __syncthreads();
  const int o = oc*256 + tid;
  const float* wr = Wout + (size_t)o*1024;
  float acc = bout[o];
  #pragma unroll 4
  for (int k=0;k<1024;k+=4) {
    float4 w = *(const float4*)(wr + k);
    acc += hsf[k]*w.x + hsf[k+1]*w.y + hsf[k+2]*w.z + hsf[k+3]*w.w;
  }
  out[(size_t)b*1024 + o] = acc;
}

extern "C" void kernel_launch(void* const* d_in, const int* in_sizes, int n_in,
                              void* d_out, int out_size, void* d_ws, size_t ws_size,
                              hipStream_t stream) {
  const float* in_seq = (const float*)d_in[0];
  const float* Wx     = (const float*)d_in[1];
  const float* bx     = (const float*)d_in[2];
  const float* Rh     = (const float*)d_in[3];
  const float* bh     = (const float*)d_in[4];
  const float* Wout   = (const float*)d_in[5];
  const float* bout   = (const float*)d_in[6];

  // ws layout (bytes)
  const size_t OFF_BAR  = 0;            // 4*1024*4        = 16384
  const size_t OFF_HBUF = 16384;        // 2*64*1024*2     = 262144
  const size_t OFF_RHB  = 278528;       // 4096*1024*2     = 8388608
  const size_t OFF_WXB  = 8667136;      // 8388608
  const size_t OFF_ABF  = 17055744;     // 65536*1024*2    = 134217728
  const size_t OFF_XP   = 151273472;    // 65536*4096*2    = 536870912
  const size_t NEED     = 688144384;
  if (ws_size < NEED) return;           // clean failure instead of corruption

  char* ws = (char*)d_ws;
  unsigned int*   bar  = (unsigned int*)  (ws + OFF_BAR);
  unsigned short* hbuf = (unsigned short*)(ws + OFF_HBUF);
  unsigned short* RhB  = (unsigned short*)(ws + OFF_RHB);
  unsigned short* WxB  = (unsigned short*)(ws + OFF_WXB);
  unsigned short* Abf  = (unsigned short*)(ws + OFF_ABF);
  unsigned short* xp   = (unsigned short*)(ws + OFF_XP);

  hipMemsetAsync(ws, 0, OFF_HBUF + 262144, stream);   // zero bar + h ring (h0 = 0)

  k_cvt <<<2048, 256, 0, stream>>>(Rh, RhB, 524288);
  k_cvt <<<2048, 256, 0, stream>>>(Wx, WxB, 524288);
  k_rein<<<65536, 128, 0, stream>>>(in_seq, Abf);
  k_gemm1<<<16384, 256, 0, stream>>>(Abf, WxB, bx, bh, xp);
  k_lstm<<<256, 512, 0, stream>>>(RhB, xp, hbuf, bar);
  k_out<<<256, 256, 0, stream>>>(hbuf, Wout, bout, (float*)d_out);
}

// Round 5
// 10655.062 us; speedup vs baseline: 5.0820x; 5.0820x over previous
//
#include <hip/hip_runtime.h>
#include <hip/hip_bf16.h>

// LSTM: B=64, S=1024, I=H=O=1024.
//  k_cvt    : Wx,Rh fp32 -> bf16
//  k_rein   : input [b][s][i] fp32 -> [s*64+b][i] bf16
//  k_gemm1  : xp[s*64+b][4096] bf16 = in @ Wx^T + bx + bh   (m97-style 128x128x64 MFMA)
//  k_lstm   : 1024 sequential steps; 4 groups x 64 blocks; Rh persistent in VGPRs.
//             Cross-block h exchange via device-scope (sc1) RELAXED atomics only:
//             no threadfence / no acquire-per-poll -> no L2 wbl2/inv storms.
//  k_out    : out[b][o] = h_final @ Wout^T + bout (fp32)

using short8 = __attribute__((ext_vector_type(8))) short;
using f32x4  = __attribute__((ext_vector_type(4))) float;

__device__ __forceinline__ float bf2f(unsigned short u) {
  union { unsigned int i; float f; } v; v.i = ((unsigned int)u) << 16; return v.f;
}
__device__ __forceinline__ unsigned short f2bf(float f) {
  unsigned int x = __float_as_uint(f);
  x += 0x7fffu + ((x >> 16) & 1u);   // RNE
  return (unsigned short)(x >> 16);
}
__device__ __forceinline__ void gload16(unsigned short* lds, const unsigned short* g) {
  __builtin_amdgcn_global_load_lds(
      (const __attribute__((address_space(1))) unsigned int*)(g),
      (__attribute__((address_space(3))) unsigned int*)(lds), 16, 0, 0);
}

// ---------------- weight convert fp32->bf16 ----------------
__global__ void k_cvt(const float* __restrict__ s, unsigned short* __restrict__ d, int n8) {
  int i = blockIdx.x * blockDim.x + threadIdx.x;
  if (i >= n8) return;
  const float4* sp = (const float4*)s + (size_t)i*2;
  float4 a = sp[0], b = sp[1];
  short8 o;
  o[0]=(short)f2bf(a.x); o[1]=(short)f2bf(a.y); o[2]=(short)f2bf(a.z); o[3]=(short)f2bf(a.w);
  o[4]=(short)f2bf(b.x); o[5]=(short)f2bf(b.y); o[6]=(short)f2bf(b.z); o[7]=(short)f2bf(b.w);
  *(short8*)(d + (size_t)i*8) = o;
}

// ---------------- input reorder+convert: [b][s][i] -> [s*64+b][i] ----------------
__global__ void k_rein(const float* __restrict__ in, unsigned short* __restrict__ out) {
  int r = blockIdx.x;               // r = s*64 + b
  int s = r >> 6, b = r & 63;
  const float* src = in + ((size_t)b*1024 + s)*1024;
  int t = threadIdx.x;              // 128 threads * 8 elems
  const float4* sp = (const float4*)(src + t*8);
  float4 a = sp[0], c = sp[1];
  short8 o;
  o[0]=(short)f2bf(a.x); o[1]=(short)f2bf(a.y); o[2]=(short)f2bf(a.z); o[3]=(short)f2bf(a.w);
  o[4]=(short)f2bf(c.x); o[5]=(short)f2bf(c.y); o[6]=(short)f2bf(c.z); o[7]=(short)f2bf(c.w);
  *(short8*)(out + (size_t)r*1024 + t*8) = o;
}

// ---------------- GEMM1: xp = A(65536x1024) * Bw^T(4096x1024) + bias, bf16 out ----------------
__launch_bounds__(256)
__global__ void k_gemm1(const unsigned short* __restrict__ A,
                        const unsigned short* __restrict__ Bw,
                        const float* __restrict__ bx,
                        const float* __restrict__ bh,
                        unsigned short* __restrict__ xp) {
  __shared__ alignas(16) unsigned short As[128*64];
  __shared__ alignas(16) unsigned short Bs[128*64];
  const int bm = blockIdx.x >> 5, bn = blockIdx.x & 31;
  const int lane = threadIdx.x & 63, wave = threadIdx.x >> 6;
  const int wm = wave >> 1, wn = wave & 1;
  const int cc = lane & 15, lg = lane >> 4;

  f32x4 acc[4][4];
  #pragma unroll
  for (int m=0;m<4;m++)
    #pragma unroll
    for (int n=0;n<4;n++) acc[m][n] = (f32x4){0.f,0.f,0.f,0.f};

  for (int kt=0; kt<16; ++kt) {
    #pragma unroll
    for (int ii=0; ii<4; ++ii) {
      int i = wave*4 + ii;
      int row = i*8 + (lane>>3);
      int gc  = kt*64 + (lane&7)*8;
      gload16(&As[i*512], A  + (size_t)(bm*128+row)*1024 + gc);
      gload16(&Bs[i*512], Bw + (size_t)(bn*128+row)*1024 + gc);
    }
    asm volatile("s_waitcnt vmcnt(0)" ::: "memory");
    __syncthreads();
    #pragma unroll
    for (int k2=0;k2<2;k2++) {
      short8 af[4], bf[4];
      #pragma unroll
      for (int m=0;m<4;m++) af[m] = *(const short8*)&As[(wm*64 + m*16 + cc)*64 + k2*32 + lg*8];
      #pragma unroll
      for (int n=0;n<4;n++) bf[n] = *(const short8*)&Bs[(wn*64 + n*16 + cc)*64 + k2*32 + lg*8];
      #pragma unroll
      for (int m=0;m<4;m++)
        #pragma unroll
        for (int n=0;n<4;n++)
          acc[m][n] = __builtin_amdgcn_mfma_f32_16x16x32_bf16(af[m], bf[n], acc[m][n], 0, 0, 0);
    }
    __syncthreads();
  }
  #pragma unroll
  for (int n=0;n<4;n++) {
    int col = bn*128 + wn*64 + n*16 + cc;
    float bias = bx[col] + bh[col];
    #pragma unroll
    for (int m=0;m<4;m++) {
      int r0 = bm*128 + wm*64 + m*16 + lg*4;
      #pragma unroll
      for (int q=0;q<4;q++)
        xp[(size_t)(r0+q)*4096 + col] = f2bf(acc[m][n][q] + bias);
    }
  }
}

// ---------------- recurrence ----------------
// grid 256 = 4 groups (16 batches) x 64 col-blocks (16 h-cols). block 512 = 8 waves.
// Rh B-frags persistent in regs. h exchanged via sc1 relaxed atomics at LLC.
__launch_bounds__(512)
__global__ void k_lstm(const unsigned short* __restrict__ RhB,
                       const unsigned short* __restrict__ xp,
                       unsigned short* __restrict__ hbuf,   // [2][64][1024] bf16
                       unsigned int* __restrict__ bar) {    // [4][1024]
  __shared__ alignas(16) unsigned short hs[16*1032];        // 16 rows, +8 shorts pad
  __shared__ alignas(16) float red[4*64*4];
  const int tid = threadIdx.x;
  const int lane = tid & 63, wv = tid >> 6;
  const int nt = wv & 3, kh = wv >> 2;
  const int grp = blockIdx.x >> 6, cb = blockIdx.x & 63;
  const int bg0 = grp*16, jb0 = cb*16;
  const int cc = lane & 15, lg = lane >> 4;
  const int ncol = (cc>>2)*1024 + jb0 + nt*4 + (cc&3);
  unsigned int* hs32 = (unsigned int*)hs;                   // padded row = 516 uints

  short8 breg[16];                                          // Rh frags, static all steps
  {
    const unsigned short* bp = RhB + (size_t)ncol*1024 + kh*512 + lg*8;
    #pragma unroll
    for (int kk=0;kk<16;kk++) breg[kk] = *(const short8*)(bp + kk*32);
  }

  float c[4] = {0.f,0.f,0.f,0.f};

  for (int t=0; t<1024; ++t) {
    const unsigned int* hprev32 =
        (const unsigned int*)(hbuf + (t&1)*65536) + bg0*512;      // group's 32KB slice
    unsigned int* hnext32 = (unsigned int*)(hbuf + ((t+1)&1)*65536);

    float xr[4];
    if (kh == 0) {                                          // xp prefetch (indep of h)
      size_t base = (size_t)(t*64 + bg0 + lg*4)*4096 + ncol;
      #pragma unroll
      for (int q=0;q<4;q++) xr[q] = bf2f(xp[base + (size_t)q*4096]);
    }

    // stage h slice -> LDS via device-scope loads (fresh from LLC, no cache inv needed)
    #pragma unroll
    for (int j=0;j<16;j++) {
      unsigned int v = __hip_atomic_load(hprev32 + j*512 + tid,
                                         __ATOMIC_RELAXED, __HIP_MEMORY_SCOPE_AGENT);
      hs32[j*516 + tid] = v;
    }
    __syncthreads();

    f32x4 acc = (f32x4){0.f,0.f,0.f,0.f};
    #pragma unroll
    for (int kk=0;kk<16;kk++) {
      short8 a = *(const short8*)&hs[cc*1032 + kh*512 + kk*32 + lg*8];
      acc = __builtin_amdgcn_mfma_f32_16x16x32_bf16(a, breg[kk], acc, 0, 0, 0);
    }

    if (kh == 1) *(f32x4*)&red[(nt*64+lane)*4] = acc;       // K-half partial
    __syncthreads();

    if (kh == 0) {
      f32x4 r2 = *(const f32x4*)&red[(nt*64+lane)*4];
      #pragma unroll
      for (int q=0;q<4;q++) {
        float v = acc[q] + r2[q] + xr[q];                   // g (bias already in xp)
        float p  = __shfl_xor(v, 4);
        float gA = (cc & 4) ? p : v;
        float gB = (cc & 4) ? v : p;
        float qA = __shfl_xor(gA, 8);
        float qB = __shfl_xor(gB, 8);
        float gz = (cc & 8) ? qA : gA;
        float gi = (cc & 8) ? qB : gB;
        float gf = (cc & 8) ? gA : qA;
        float go = (cc & 8) ? gB : qB;
        float zt = 2.f/(1.f+__expf(-2.f*gz)) - 1.f;
        float is = 1.f/(1.f+__expf(-gi));
        float fs = 1.f/(1.f+__expf(-gf));
        float os = 1.f/(1.f+__expf(-go));
        float cn = fs*c[q] + is*zt;
        c[q] = cn;
        float hv = os*(2.f/(1.f+__expf(-2.f*cn)) - 1.f);
        float hp = __shfl_xor(hv, 1);                       // partner col for u32 pack
        if ((cc & 1) == 0 && cc < 4) {                      // lanes cc=0,2 store col pairs
          unsigned int pk = (unsigned int)f2bf(hv) | ((unsigned int)f2bf(hp) << 16);
          int row = bg0 + lg*4 + q;
          __hip_atomic_store(hnext32 + row*512 + ((jb0 + nt*4 + cc) >> 1), pk,
                             __ATOMIC_RELAXED, __HIP_MEMORY_SCOPE_AGENT);
        }
      }
    }

    asm volatile("s_waitcnt vmcnt(0)" ::: "memory");        // sc1 stores at LLC
    __syncthreads();                                        // all waves' stores done
    if (tid == 0) {
      unsigned int* flag = bar + grp*1024 + t;
      __hip_atomic_fetch_add(flag, 1u, __ATOMIC_RELAXED, __HIP_MEMORY_SCOPE_AGENT);
      unsigned int spins = 0;
      while (__hip_atomic_load(flag, __ATOMIC_RELAXED, __HIP_MEMORY_SCOPE_AGENT) < 64u) {
        __builtin_amdgcn_s_sleep(1);
        if (++spins > 500000u) break;                       // bail-out: no hangs
      }
      // single cheap hedge vs any stale-L2-hit corner case (1 inv/block/step)
      __scoped_atomic_thread_fence(__ATOMIC_ACQUIRE, __MEMORY_SCOPE_DEVICE);
    }
    __syncthreads();
  }
}

// ---------------- final: out = h @ Wout^T + bout (fp32) ----------------
__global__ void k_out(const unsigned short* __restrict__ h,
                      const float* __restrict__ Wout,
                      const float* __restrict__ bout,
                      float* __restrict__ out) {
  __shared__ float hsf[1024];
  const int b = blockIdx.x >> 2, oc = blockIdx.x & 3;
  const int tid = threadIdx.x;
  const unsigned short* hr = h + (size_t)b*1024;
  #pragma unroll
  for (int j=0;j<4;j++) hsf[tid*4+j] = bf2f(hr[tid*4+j]);
  __syncthreads();
  const int o = oc*256 + tid;
  const float* wr = Wout + (size_t)o*1024;
  float acc = bout[o];
  #pragma unroll 4
  for (int k=0;k<1024;k+=4) {
    float4 w = *(const float4*)(wr + k);
    acc += hsf[k]*w.x + hsf[k+1]*w.y + hsf[k+2]*w.z + hsf[k+3]*w.w;
  }
  out[(size_t)b*1024 + o] = acc;
}

extern "C" void kernel_launch(void* const* d_in, const int* in_sizes, int n_in,
                              void* d_out, int out_size, void* d_ws, size_t ws_size,
                              hipStream_t stream) {
  const float* in_seq = (const float*)d_in[0];
  const float* Wx     = (const float*)d_in[1];
  const float* bx     = (const float*)d_in[2];
  const float* Rh     = (const float*)d_in[3];
  const float* bh     = (const float*)d_in[4];
  const float* Wout   = (const float*)d_in[5];
  const float* bout   = (const float*)d_in[6];

  const size_t OFF_BAR  = 0;            // 16384
  const size_t OFF_HBUF = 16384;        // 262144
  const size_t OFF_RHB  = 278528;       // 8388608
  const size_t OFF_WXB  = 8667136;      // 8388608
  const size_t OFF_ABF  = 17055744;     // 134217728
  const size_t OFF_XP   = 151273472;    // 536870912
  const size_t NEED     = 688144384;
  if (ws_size < NEED) return;

  char* ws = (char*)d_ws;
  unsigned int*   bar  = (unsigned int*)  (ws + OFF_BAR);
  unsigned short* hbuf = (unsigned short*)(ws + OFF_HBUF);
  unsigned short* RhB  = (unsigned short*)(ws + OFF_RHB);
  unsigned short* WxB  = (unsigned short*)(ws + OFF_WXB);
  unsigned short* Abf  = (unsigned short*)(ws + OFF_ABF);
  unsigned short* xp   = (unsigned short*)(ws + OFF_XP);

  (void)hipMemsetAsync(ws, 0, OFF_HBUF + 262144, stream);   // zero bar + h ring

  k_cvt <<<2048, 256, 0, stream>>>(Rh, RhB, 524288);
  k_cvt <<<2048, 256, 0, stream>>>(Wx, WxB, 524288);
  k_rein<<<65536, 128, 0, stream>>>(in_seq, Abf);
  k_gemm1<<<16384, 256, 0, stream>>>(Abf, WxB, bx, bh, xp);
  k_lstm<<<256, 512, 0, stream>>>(RhB, xp, hbuf, bar);
  k_out<<<256, 256, 0, stream>>>(hbuf, Wout, bout, (float*)d_out);
}

// Round 6
// 7454.909 us; speedup vs baseline: 7.2636x; 1.4293x over previous
//
#include <hip/hip_runtime.h>
#include <hip/hip_bf16.h>

// LSTM: B=64, S=1024, I=H=O=1024.
//  k_cvt    : Wx,Rh fp32 -> bf16
//  k_rein   : input [b][s][i] fp32 -> [s*64+b][i] bf16
//  k_gemm1  : xp[s*64+b][4096] bf16 = in @ Wx^T + bx + bh   (m97-style 128x128x64 MFMA)
//  k_lstm   : 1024 sequential steps; 4 groups x 64 blocks; Rh persistent in VGPRs.
//             h exchange via LLC-coherent (sc0 sc1) loads/stores, relaxed atomics for
//             the flag, NO cache-maintenance ops anywhere in the loop (no fence/inv).
//  k_out    : out[b][o] = h_final @ Wout^T + bout (fp32)

using short8 = __attribute__((ext_vector_type(8))) short;
using f32x4  = __attribute__((ext_vector_type(4))) float;
using u32x4  = __attribute__((ext_vector_type(4))) unsigned int;

__device__ __forceinline__ float bf2f(unsigned short u) {
  union { unsigned int i; float f; } v; v.i = ((unsigned int)u) << 16; return v.f;
}
__device__ __forceinline__ unsigned short f2bf(float f) {
  unsigned int x = __float_as_uint(f);
  x += 0x7fffu + ((x >> 16) & 1u);   // RNE
  return (unsigned short)(x >> 16);
}
__device__ __forceinline__ void gload16(unsigned short* lds, const unsigned short* g) {
  __builtin_amdgcn_global_load_lds(
      (const __attribute__((address_space(1))) unsigned int*)(g),
      (__attribute__((address_space(3))) unsigned int*)(lds), 16, 0, 0);
}
// coherent 16B load: bypasses L1/L2, reads the LLC coherence point directly
__device__ __forceinline__ u32x4 ld16_coh(const unsigned int* p) {
  u32x4 r;
  asm volatile("global_load_dwordx4 %0, %1, off sc0 sc1" : "=v"(r) : "v"(p));
  return r;
}

// ---------------- weight convert fp32->bf16 ----------------
__global__ void k_cvt(const float* __restrict__ s, unsigned short* __restrict__ d, int n8) {
  int i = blockIdx.x * blockDim.x + threadIdx.x;
  if (i >= n8) return;
  const float4* sp = (const float4*)s + (size_t)i*2;
  float4 a = sp[0], b = sp[1];
  short8 o;
  o[0]=(short)f2bf(a.x); o[1]=(short)f2bf(a.y); o[2]=(short)f2bf(a.z); o[3]=(short)f2bf(a.w);
  o[4]=(short)f2bf(b.x); o[5]=(short)f2bf(b.y); o[6]=(short)f2bf(b.z); o[7]=(short)f2bf(b.w);
  *(short8*)(d + (size_t)i*8) = o;
}

// ---------------- input reorder+convert: [b][s][i] -> [s*64+b][i] ----------------
__global__ void k_rein(const float* __restrict__ in, unsigned short* __restrict__ out) {
  int r = blockIdx.x;               // r = s*64 + b
  int s = r >> 6, b = r & 63;
  const float* src = in + ((size_t)b*1024 + s)*1024;
  int t = threadIdx.x;              // 128 threads * 8 elems
  const float4* sp = (const float4*)(src + t*8);
  float4 a = sp[0], c = sp[1];
  short8 o;
  o[0]=(short)f2bf(a.x); o[1]=(short)f2bf(a.y); o[2]=(short)f2bf(a.z); o[3]=(short)f2bf(a.w);
  o[4]=(short)f2bf(c.x); o[5]=(short)f2bf(c.y); o[6]=(short)f2bf(c.z); o[7]=(short)f2bf(c.w);
  *(short8*)(out + (size_t)r*1024 + t*8) = o;
}

// ---------------- GEMM1: xp = A(65536x1024) * Bw^T(4096x1024) + bias, bf16 out ----------------
__launch_bounds__(256)
__global__ void k_gemm1(const unsigned short* __restrict__ A,
                        const unsigned short* __restrict__ Bw,
                        const float* __restrict__ bx,
                        const float* __restrict__ bh,
                        unsigned short* __restrict__ xp) {
  __shared__ alignas(16) unsigned short As[128*64];
  __shared__ alignas(16) unsigned short Bs[128*64];
  const int bm = blockIdx.x >> 5, bn = blockIdx.x & 31;
  const int lane = threadIdx.x & 63, wave = threadIdx.x >> 6;
  const int wm = wave >> 1, wn = wave & 1;
  const int cc = lane & 15, lg = lane >> 4;

  f32x4 acc[4][4];
  #pragma unroll
  for (int m=0;m<4;m++)
    #pragma unroll
    for (int n=0;n<4;n++) acc[m][n] = (f32x4){0.f,0.f,0.f,0.f};

  for (int kt=0; kt<16; ++kt) {
    #pragma unroll
    for (int ii=0; ii<4; ++ii) {
      int i = wave*4 + ii;
      int row = i*8 + (lane>>3);
      int gc  = kt*64 + (lane&7)*8;
      gload16(&As[i*512], A  + (size_t)(bm*128+row)*1024 + gc);
      gload16(&Bs[i*512], Bw + (size_t)(bn*128+row)*1024 + gc);
    }
    asm volatile("s_waitcnt vmcnt(0)" ::: "memory");
    __syncthreads();
    #pragma unroll
    for (int k2=0;k2<2;k2++) {
      short8 af[4], bf[4];
      #pragma unroll
      for (int m=0;m<4;m++) af[m] = *(const short8*)&As[(wm*64 + m*16 + cc)*64 + k2*32 + lg*8];
      #pragma unroll
      for (int n=0;n<4;n++) bf[n] = *(const short8*)&Bs[(wn*64 + n*16 + cc)*64 + k2*32 + lg*8];
      #pragma unroll
      for (int m=0;m<4;m++)
        #pragma unroll
        for (int n=0;n<4;n++)
          acc[m][n] = __builtin_amdgcn_mfma_f32_16x16x32_bf16(af[m], bf[n], acc[m][n], 0, 0, 0);
    }
    __syncthreads();
  }
  #pragma unroll
  for (int n=0;n<4;n++) {
    int col = bn*128 + wn*64 + n*16 + cc;
    float bias = bx[col] + bh[col];
    #pragma unroll
    for (int m=0;m<4;m++) {
      int r0 = bm*128 + wm*64 + m*16 + lg*4;
      #pragma unroll
      for (int q=0;q<4;q++)
        xp[(size_t)(r0+q)*4096 + col] = f2bf(acc[m][n][q] + bias);
    }
  }
}

// ---------------- recurrence ----------------
// grid 256 = 4 groups (16 batches) x 64 col-blocks (16 h-cols). block 512 = 8 waves.
// Rh B-frags persistent in regs. h exchanged via sc0sc1 loads / sc1 relaxed stores.
// ZERO cache-maintenance instructions in the step loop.
__launch_bounds__(512)
__global__ void k_lstm(const unsigned short* __restrict__ RhB,
                       const unsigned short* __restrict__ xp,
                       unsigned short* __restrict__ hbuf,   // [2][64][1024] bf16
                       unsigned int* __restrict__ bar) {    // [4][1024]
  __shared__ alignas(16) unsigned short hs[16*1032];        // 16 rows, +8 shorts pad
  __shared__ alignas(16) float red[4*64*4];
  const int tid = threadIdx.x;
  const int lane = tid & 63, wv = tid >> 6;
  const int nt = wv & 3, kh = wv >> 2;
  const int grp = blockIdx.x >> 6, cb = blockIdx.x & 63;
  const int bg0 = grp*16, jb0 = cb*16;
  const int cc = lane & 15, lg = lane >> 4;
  const int ncol = (cc>>2)*1024 + jb0 + nt*4 + (cc&3);
  unsigned int* hs32 = (unsigned int*)hs;                   // padded row = 516 uints

  short8 breg[16];                                          // Rh frags, static all steps
  {
    const unsigned short* bp = RhB + (size_t)ncol*1024 + kh*512 + lg*8;
    #pragma unroll
    for (int kk=0;kk<16;kk++) breg[kk] = *(const short8*)(bp + kk*32);
  }

  float c[4] = {0.f,0.f,0.f,0.f};
  unsigned short xr[4], xrn[4];
  if (kh == 0) {                                            // preload xp for t=0
    size_t base = (size_t)(bg0 + lg*4)*4096 + ncol;
    #pragma unroll
    for (int q=0;q<4;q++) xr[q] = xp[base + (size_t)q*4096];
  }

  for (int t=0; t<1024; ++t) {
    const unsigned int* hprev32 =
        (const unsigned int*)(hbuf + (t&1)*65536) + bg0*512;      // group's 32KB slice
    unsigned int* hnext32 = (unsigned int*)(hbuf + ((t+1)&1)*65536);

    // ---- stage h slice -> LDS: 4x coherent dwordx4 per thread (32KB total) ----
    {
      u32x4 stg[4];
      const unsigned int* gb = hprev32 + tid*4;
      #pragma unroll
      for (int r=0;r<4;r++) stg[r] = ld16_coh(gb + r*2048);
      asm volatile("s_waitcnt vmcnt(0)" ::: "memory");
      __builtin_amdgcn_sched_barrier(0);
      #pragma unroll
      for (int r=0;r<4;r++) {
        int row = r*4 + (tid>>7);
        *(u32x4*)&hs32[row*516 + (tid&127)*4] = stg[r];
      }
    }
    // xp prefetch for t+1 (raw ushorts; converted at use next step; hides under barrier)
    if (kh == 0 && t < 1023) {
      size_t base = (size_t)((t+1)*64 + bg0 + lg*4)*4096 + ncol;
      #pragma unroll
      for (int q=0;q<4;q++) xrn[q] = xp[base + (size_t)q*4096];
    }
    __syncthreads();

    f32x4 acc = (f32x4){0.f,0.f,0.f,0.f};
    #pragma unroll
    for (int kk=0;kk<16;kk++) {
      short8 a = *(const short8*)&hs[cc*1032 + kh*512 + kk*32 + lg*8];
      acc = __builtin_amdgcn_mfma_f32_16x16x32_bf16(a, breg[kk], acc, 0, 0, 0);
    }

    if (kh == 1) *(f32x4*)&red[(nt*64+lane)*4] = acc;       // K-half partial
    __syncthreads();

    if (kh == 0) {
      f32x4 r2 = *(const f32x4*)&red[(nt*64+lane)*4];
      #pragma unroll
      for (int q=0;q<4;q++) {
        float v = acc[q] + r2[q] + bf2f(xr[q]);             // g (bias already in xp)
        float p  = __shfl_xor(v, 4);
        float gA = (cc & 4) ? p : v;
        float gB = (cc & 4) ? v : p;
        float qA = __shfl_xor(gA, 8);
        float qB = __shfl_xor(gB, 8);
        float gz = (cc & 8) ? qA : gA;
        float gi = (cc & 8) ? qB : gB;
        float gf = (cc & 8) ? gA : qA;
        float go = (cc & 8) ? gB : qB;
        float zt = 2.f/(1.f+__expf(-2.f*gz)) - 1.f;
        float is = 1.f/(1.f+__expf(-gi));
        float fs = 1.f/(1.f+__expf(-gf));
        float os = 1.f/(1.f+__expf(-go));
        float cn = fs*c[q] + is*zt;
        c[q] = cn;
        float hv = os*(2.f/(1.f+__expf(-2.f*cn)) - 1.f);
        float hp = __shfl_xor(hv, 1);                       // partner col for u32 pack
        if ((cc & 1) == 0 && cc < 4) {                      // lanes cc=0,2 store col pairs
          unsigned int pk = (unsigned int)f2bf(hv) | ((unsigned int)f2bf(hp) << 16);
          int row = bg0 + lg*4 + q;
          __hip_atomic_store(hnext32 + row*512 + ((jb0 + nt*4 + cc) >> 1), pk,
                             __ATOMIC_RELAXED, __HIP_MEMORY_SCOPE_AGENT);
        }
      }
      #pragma unroll
      for (int q=0;q<4;q++) xr[q] = xrn[q];                 // rotate prefetch regs
    }

    asm volatile("s_waitcnt vmcnt(0)" ::: "memory");        // h stores at LLC
    __syncthreads();                                        // all waves' stores done
    if (tid == 0) {
      unsigned int* flag = bar + grp*1024 + t;
      __hip_atomic_fetch_add(flag, 1u, __ATOMIC_RELAXED, __HIP_MEMORY_SCOPE_AGENT);
      unsigned int spins = 0;
      while (__hip_atomic_load(flag, __ATOMIC_RELAXED, __HIP_MEMORY_SCOPE_AGENT) < 64u) {
        __builtin_amdgcn_s_sleep(1);
        if (++spins > 500000u) break;                       // bail-out: no hangs
      }
      // NOTE: no acquire fence — all racing reads use sc0/sc1 LLC-coherent loads
    }
    __syncthreads();
  }
}

// ---------------- final: out = h @ Wout^T + bout (fp32) ----------------
__global__ void k_out(const unsigned short* __restrict__ h,
                      const float* __restrict__ Wout,
                      const float* __restrict__ bout,
                      float* __restrict__ out) {
  __shared__ float hsf[1024];
  const int b = blockIdx.x >> 2, oc = blockIdx.x & 3;
  const int tid = threadIdx.x;
  const unsigned short* hr = h + (size_t)b*1024;
  #pragma unroll
  for (int j=0;j<4;j++) hsf[tid*4+j] = bf2f(hr[tid*4+j]);
  __syncthreads();
  const int o = oc*256 + tid;
  const float* wr = Wout + (size_t)o*1024;
  float acc = bout[o];
  #pragma unroll 4
  for (int k=0;k<1024;k+=4) {
    float4 w = *(const float4*)(wr + k);
    acc += hsf[k]*w.x + hsf[k+1]*w.y + hsf[k+2]*w.z + hsf[k+3]*w.w;
  }
  out[(size_t)b*1024 + o] = acc;
}

extern "C" void kernel_launch(void* const* d_in, const int* in_sizes, int n_in,
                              void* d_out, int out_size, void* d_ws, size_t ws_size,
                              hipStream_t stream) {
  const float* in_seq = (const float*)d_in[0];
  const float* Wx     = (const float*)d_in[1];
  const float* bx     = (const float*)d_in[2];
  const float* Rh     = (const float*)d_in[3];
  const float* bh     = (const float*)d_in[4];
  const float* Wout   = (const float*)d_in[5];
  const float* bout   = (const float*)d_in[6];

  const size_t OFF_BAR  = 0;            // 16384
  const size_t OFF_HBUF = 16384;        // 262144
  const size_t OFF_RHB  = 278528;       // 8388608
  const size_t OFF_WXB  = 8667136;      // 8388608
  const size_t OFF_ABF  = 17055744;     // 134217728
  const size_t OFF_XP   = 151273472;    // 536870912
  const size_t NEED     = 688144384;
  if (ws_size < NEED) return;

  char* ws = (char*)d_ws;
  unsigned int*   bar  = (unsigned int*)  (ws + OFF_BAR);
  unsigned short* hbuf = (unsigned short*)(ws + OFF_HBUF);
  unsigned short* RhB  = (unsigned short*)(ws + OFF_RHB);
  unsigned short* WxB  = (unsigned short*)(ws + OFF_WXB);
  unsigned short* Abf  = (unsigned short*)(ws + OFF_ABF);
  unsigned short* xp   = (unsigned short*)(ws + OFF_XP);

  (void)hipMemsetAsync(ws, 0, OFF_HBUF + 262144, stream);   // zero bar + h ring

  k_cvt <<<2048, 256, 0, stream>>>(Rh, RhB, 524288);
  k_cvt <<<2048, 256, 0, stream>>>(Wx, WxB, 524288);
  k_rein<<<65536, 128, 0, stream>>>(in_seq, Abf);
  k_gemm1<<<16384, 256, 0, stream>>>(Abf, WxB, bx, bh, xp);
  k_lstm<<<256, 512, 0, stream>>>(RhB, xp, hbuf, bar);
  k_out<<<256, 256, 0, stream>>>(hbuf, Wout, bout, (float*)d_out);
}